// Round 9
// baseline (154.777 us; speedup 1.0000x reference)
//
#include <hip/hip_runtime.h>
#include <math.h>

#define W_IMG 2048
#define H_IMG 64
#define B_IMG 8
#define C_IMG 7
#define NPIX (B_IMG * H_IMG * W_IMG)

__device__ __forceinline__ float F(unsigned u) { return __uint_as_float(u); }
#define FMAF(a,b,c) __builtin_fmaf((a),(b),(c))

// ---------------------------------------------------------------------------
// Bit-exact glibc (<=2.39) scalar s_atanf.c — original 11-coefficient fdlibm
// float port, baseline x86-64 build (no FMA available -> op-by-op IEEE).
// ---------------------------------------------------------------------------
__device__ __forceinline__ float glibc_atanf(float x) {
    const float atanhi[4] = {F(0x3eed6338u), F(0x3f490fdau), F(0x3f7b985eu), F(0x3fc90fdau)};
    const float atanlo[4] = {F(0x31ac3769u), F(0x33222168u), F(0x33140fb4u), F(0x33a22168u)};
    const float aT0 = F(0x3eaaaaabu), aT1 = F(0xbe4ccccdu), aT2 = F(0x3e124925u),
                aT3 = F(0xbde38e38u), aT4 = F(0x3dba2e6eu), aT5 = F(0xbd9d8795u),
                aT6 = F(0x3d886b35u), aT7 = F(0xbd6ef16bu), aT8 = F(0x3d4bda59u),
                aT9 = F(0xbd15a221u), aT10 = F(0x3c8569d7u);

    unsigned hx = __float_as_uint(x);
    unsigned ix = hx & 0x7fffffffu;
    if (ix >= 0x4c800000u) {                     // |x| >= 2^26
        if (ix > 0x7f800000u) return x + x;      // NaN
        float v = __fadd_rn(atanhi[3], atanlo[3]);
        return (hx >> 31) ? -v : v;
    }
    int id;
    float xr = x;
    if (ix < 0x3ee00000u) {                      // |x| < 0.4375
        if (ix < 0x31000000u) return x;          // |x| < 2^-29
        id = -1;
    } else {
        xr = fabsf(x);
        if (ix < 0x3f980000u) {                  // |x| < 1.1875
            if (ix < 0x3f300000u) {              // [7/16, 11/16)
                id = 0;
                xr = __fdiv_rn(__fsub_rn(__fmul_rn(2.0f, xr), 1.0f),
                               __fadd_rn(2.0f, xr));
            } else {                             // [11/16, 19/16)
                id = 1;
                xr = __fdiv_rn(__fsub_rn(xr, 1.0f), __fadd_rn(xr, 1.0f));
            }
        } else {
            if (ix < 0x401c0000u) {              // [19/16, 39/16)
                id = 2;
                xr = __fdiv_rn(__fsub_rn(xr, 1.5f),
                               __fadd_rn(1.0f, __fmul_rn(1.5f, xr)));
            } else {                             // [39/16, 2^26)
                id = 3;
                xr = __fdiv_rn(-1.0f, xr);
            }
        }
    }
    float z = __fmul_rn(xr, xr);
    float w = __fmul_rn(z, z);
    float s1 = __fmul_rn(z, __fadd_rn(aT0, __fmul_rn(w, __fadd_rn(aT2,
               __fmul_rn(w, __fadd_rn(aT4, __fmul_rn(w, __fadd_rn(aT6,
               __fmul_rn(w, __fadd_rn(aT8, __fmul_rn(w, aT10)))))))))));
    float s2 = __fmul_rn(w, __fadd_rn(aT1, __fmul_rn(w, __fadd_rn(aT3,
               __fmul_rn(w, __fadd_rn(aT5, __fmul_rn(w, __fadd_rn(aT7,
               __fmul_rn(w, aT9)))))))));
    if (id < 0) return __fsub_rn(x, __fmul_rn(x, __fadd_rn(s1, s2)));
    const float hi[4] = {atanhi[0], atanhi[1], atanhi[2], atanhi[3]};
    const float lo[4] = {atanlo[0], atanlo[1], atanlo[2], atanlo[3]};
    float zz = __fsub_rn(hi[id],
               __fsub_rn(__fsub_rn(__fmul_rn(xr, __fadd_rn(s1, s2)), lo[id]), xr));
    return (hx >> 31) ? -zz : zz;
}

// glibc scalar e_atan2f.c (fdlibm float port), bit-exact.
__device__ __forceinline__ float glibc_atan2f(float y, float x) {
    const float pi_o_2 = F(0x3fc90fdbu);
    const float pi     = F(0x40490fdbu);
    const float pi_lo  = F(0xb3bbbd2eu);
    unsigned hx = __float_as_uint(x), hy = __float_as_uint(y);
    unsigned ix = hx & 0x7fffffffu, iy = hy & 0x7fffffffu;
    if (ix > 0x7f800000u || iy > 0x7f800000u) return x + y;
    if (hx == 0x3f800000u) return glibc_atanf(y);
    unsigned m = ((hy >> 31) & 1u) | ((hx >> 30) & 2u);
    if (iy == 0) {
        switch (m) {
            case 0: case 1: return y;
            case 2: return pi;
            default: return -pi;
        }
    }
    if (ix == 0) return (m & 1u) ? -pi_o_2 : pi_o_2;
    if (ix == 0x7f800000u) {
        if (iy == 0x7f800000u) {
            switch (m) {
                case 0: return F(0x3f490fdbu);
                case 1: return -F(0x3f490fdbu);
                case 2: return __fmul_rn(3.0f, F(0x3f490fdbu));
                default: return -__fmul_rn(3.0f, F(0x3f490fdbu));
            }
        } else {
            switch (m) {
                case 0: return 0.0f;
                case 1: return -0.0f;
                case 2: return pi;
                default: return -pi;
            }
        }
    }
    if (iy == 0x7f800000u) return (m & 1u) ? -pi_o_2 : pi_o_2;

    int k = ((int)iy - (int)ix) >> 23;
    float z;
    if (k > 26) {
        z = __fadd_rn(pi_o_2, __fmul_rn(0.5f, pi_lo));
        m &= 1u;
    } else if (k < -26 && (hx >> 31)) {
        z = 0.0f;
    } else {
        z = glibc_atanf(fabsf(__fdiv_rn(y, x)));
    }
    switch (m) {
        case 0: return z;
        case 1: return __uint_as_float(__float_as_uint(z) ^ 0x80000000u);
        case 2: return __fsub_rn(pi, __fsub_rn(z, pi_lo));
        default: return __fsub_rn(__fsub_rn(z, pi_lo), pi);
    }
}

// ---------------------------------------------------------------------------
// XLA:CPU fast-math pipeline replica:
//   r     = sqrt(fma(z,z, fma(y,y, x*x)))        [contracted reduce]
//   theta = -atan2f(y,x)                          [scalar glibc libcall]
//   phi   = -asin(zr); CHLO: asin(x)=2*atan2(x, 1+sqrt(1-x*x)),
//           1-x*x contracted -> fma(-x,x,1)
//   u_n   = (theta - H0) * (1/SPANH)              [div-by-const -> recip mul]
//   v_n   = (phi   - V0) * (1/SPANV)
// Reciprocals folded at compile time with IEEE rounding (matches LLVM fold).
// ---------------------------------------------------------------------------
struct Proj {
    float r, theta, phi;
    int   pix;
    bool  in_image;
};

__device__ __forceinline__ Proj project_point(float x, float y, float z, float bsf) {
    const float H0F   = (float)(-3.14159265358979323846);
    const float SPANH = (float)( 6.28318530717958647692);
    const float V0F   = (float)(-3.0 * 3.14159265358979323846 / 180.0);
    const float SPANV = (float)((25.0 * 3.14159265358979323846 / 180.0) -
                                (-3.0 * 3.14159265358979323846 / 180.0));
    const float RH = 1.0f / SPANH;   // compile-time IEEE fold
    const float RV = 1.0f / SPANV;

    Proj p;
    p.r = __fsqrt_rn(FMAF(z, z, FMAF(y, y, __fmul_rn(x, x))));
    p.theta = -glibc_atan2f(y, x);

    float zr = __fdiv_rn(z, fmaxf(p.r, 1e-5f));
    // asin(zr) = 2*atan2(zr, 1 + sqrt(fma(-zr,zr,1)))
    float s  = __fsqrt_rn(FMAF(-zr, zr, 1.0f));
    float d  = __fadd_rn(1.0f, s);
    p.phi = -__fmul_rn(2.0f, glibc_atan2f(zr, d));

    float u_n = __fmul_rn(__fsub_rn(p.theta, H0F), RH);
    float v_n = __fmul_rn(__fsub_rn(p.phi,   V0F), RV);
    p.in_image = (u_n >= 0.0f) && (u_n < 1.0f) && (v_n >= 0.0f) && (v_n < 1.0f);
    p.pix = -1;
    if (p.in_image) {
        int u = (int)__fmul_rn(u_n, (float)W_IMG);   // exact pow2 mul, trunc
        int v = (int)__fmul_rn(v_n, (float)H_IMG);
        int b = (int)bsf;
        if (u < W_IMG && v < H_IMG) {
            p.pix = (b * H_IMG + v) * W_IMG + u;
        } else {
            p.in_image = false;                      // mode='drop'
        }
    }
    return p;
}

__global__ void init_winner(int4* winner4, int n4) {
    int i = blockIdx.x * blockDim.x + threadIdx.x;
    if (i < n4) winner4[i] = make_int4(-1, -1, -1, -1);
}

__global__ void scatter_winner(const float* __restrict__ pts, int* __restrict__ winner, int n) {
    int i = blockIdx.x * blockDim.x + threadIdx.x;
    if (i >= n) return;
    const float* q = pts + (size_t)i * 5;
    Proj p = project_point(q[1], q[2], q[3], q[0]);
    if (p.in_image) {
        atomicMax(&winner[p.pix], i);   // last (highest index) wins
    }
}

__global__ void write_output(const float* __restrict__ pts, const int* __restrict__ winner,
                             float* __restrict__ out) {
    int p = blockIdx.x * blockDim.x + threadIdx.x;
    if (p >= NPIX) return;
    int wi = winner[p];
    int b  = p / (H_IMG * W_IMG);
    int hw = p - b * (H_IMG * W_IMG);

    float feat[C_IMG] = {0.f, 0.f, 0.f, 0.f, 0.f, 0.f, 0.f};
    if (wi >= 0) {
        const float* q = pts + (size_t)wi * 5;
        Proj pr = project_point(q[1], q[2], q[3], q[0]);
        feat[0] = q[1]; feat[1] = q[2]; feat[2] = q[3];
        feat[3] = pr.r; feat[4] = pr.theta; feat[5] = pr.phi;
        feat[6] = q[4];
    }
    size_t base = (size_t)b * C_IMG * H_IMG * W_IMG + hw;
#pragma unroll
    for (int c = 0; c < C_IMG; ++c) {
        out[base + (size_t)c * H_IMG * W_IMG] = feat[c];
    }
}

extern "C" void kernel_launch(void* const* d_in, const int* in_sizes, int n_in,
                              void* d_out, int out_size, void* d_ws, size_t ws_size,
                              hipStream_t stream) {
    const float* pts = (const float*)d_in[0];
    int n = in_sizes[0] / 5;
    int* winner = (int*)d_ws;              // B*H*W ints = 4 MB scratch
    float* out = (float*)d_out;

    int n4 = NPIX / 4;
    init_winner<<<(n4 + 255) / 256, 256, 0, stream>>>((int4*)winner, n4);
    scatter_winner<<<(n + 255) / 256, 256, 0, stream>>>(pts, winner, n);
    write_output<<<(NPIX + 255) / 256, 256, 0, stream>>>(pts, winner, out);
}